// Round 4
// baseline (59586.261 us; speedup 1.0000x reference)
//
#include <hip/hip_runtime.h>

typedef unsigned short u16;
typedef unsigned int u32;
typedef unsigned long long u64;
typedef __attribute__((ext_vector_type(8))) short bf16x8;   // 8 bf16 = 4 VGPRs
typedef __attribute__((ext_vector_type(4))) float f32x4;

#define LL 4
#define NN 32
#define SS 2048
#define VV 512
#define DD 512
#define CHUNK 16
#define NCHUNKS (SS / CHUNK)              // 128

#define NCONS 8
#define NBLOCKS 256
#define FGROUPS 4                          // 128 feats per producer combo
#define NCOMBOS 32                         // 8 cl x 4 fg
#define CRES 7                             // chunk residues per combo
#define NPROD_ACTIVE (NCOMBOS * CRES)      // 224 persistent producer blocks

// ws layout
#define PRODCNT_OFF 0                      // u32[8][NCHUNKS]
#define CONSDONE_OFF (NCONS * NCHUNKS * 4) // u32[8], 128B-padded
#define RING_OFF 8192
#define SLOT_BYTES ((size_t)NCONS * CHUNK * 8 * 64 * 32)   // 2 MB: [cl][t][w][lane][32B]

// LDS: 128K Wh-tile3 / producer B-stage  +  2 x 16K double-buffered h (XOR-swizzled).
// The XOR layout was HW-validated in rounds 1-2: absmax identical (0.00390625) and
// SQ_LDS_BANK_CONFLICT bit-identical to the PADR=520 layout -> conflict-neutral.
#define HB_OFF 131072
#define HB_BYTES 16384
#define LDS_BYTES (HB_OFF + 2 * HB_BYTES)  // 163840 = full 160 KiB

static __device__ __forceinline__ u16 f2bf(float f) {
    u32 x = __float_as_uint(f);
    x += 0x7fffu + ((x >> 16) & 1u);       // round-to-nearest-even
    return (u16)(x >> 16);
}
static __device__ __forceinline__ float bf2f(u32 h) {
    return __uint_as_float((h & 0xffffu) << 16);
}
static __device__ __forceinline__ bf16x8 cvt8(const float* p) {
    f32x4 a = *(const f32x4*)p;
    f32x4 b = *(const f32x4*)(p + 4);
    bf16x8 r;
    r[0] = (short)f2bf(a[0]); r[1] = (short)f2bf(a[1]);
    r[2] = (short)f2bf(a[2]); r[3] = (short)f2bf(a[3]);
    r[4] = (short)f2bf(b[0]); r[5] = (short)f2bf(b[1]);
    r[6] = (short)f2bf(b[2]); r[7] = (short)f2bf(b[3]);
    return r;
}

__global__ __launch_bounds__(512, 2) void rnn_fused(
    const float* __restrict__ x,   // [N][S][V]
    const float* __restrict__ Wx,  // [L][D][V]
    const float* __restrict__ bx,  // [L][D]
    const float* __restrict__ Wh,  // [L][D][D]
    const float* __restrict__ bh,  // [L][D]
    float* __restrict__ out,       // [N][S][D] ++ [L][N][D]
    char* __restrict__ ws, int nslots)
{
    extern __shared__ __align__(16) char lds[];
    const int tid = threadIdx.x;
    const int lane = tid & 63;
    const int w = tid >> 6;                // wave 0..7
    const int col = lane & 15, quad = lane >> 4;
    u32* prod_cnt = (u32*)(ws + PRODCNT_OFF);    // [cl][chunk]
    u32* cons_done = (u32*)(ws + CONSDONE_OFF);  // [cl*32]
    char* ring = ws + RING_OFF;

    if (blockIdx.x < NCONS) {
        // ========== consumer: sequential scan, ONE barrier per step (h double-buffer) ==========
        const int cl = blockIdx.x;
        const int layer = cl >> 1, nb = cl & 1;
        u16* whlds = (u16*)lds;                   // [w][ks][lane][8 bf16] = 128 KB (tile 3)

        // Wh: tiles 0..2 -> registers, tile 3 -> LDS
        bf16x8 whf[48];
#pragma unroll
        for (int tl = 0; tl < 3; ++tl)
#pragma unroll
            for (int ks = 0; ks < 16; ++ks)
                whf[tl * 16 + ks] =
                    cvt8(Wh + ((size_t)layer * DD + (w * 64 + tl * 16 + col)) * DD + 32 * ks + quad * 8);
#pragma unroll
        for (int ks = 0; ks < 16; ++ks) {
            bf16x8 f = cvt8(Wh + ((size_t)layer * DD + (w * 64 + 48 + col)) * DD + 32 * ks + quad * 8);
            *(bf16x8*)(whlds + ((size_t)(w * 16 + ks) * 64 + lane) * 8) = f;
        }
        // zero both h buffers (h[-1] = 0)
        for (int i = tid; i < 2 * HB_BYTES / 4; i += 512) ((u32*)(lds + HB_OFF))[i] = 0u;
        __syncthreads();

        auto xp_addr = [&](int t) -> const u64* {
            const int slot = (t >> 4) % nslots;
            return (const u64*)(ring +
                ((((size_t)(slot * NCONS + cl) * CHUNK + (t & 15)) * 8 + w) * 64 + lane) * 32);
        };
        // wait chunk 0, preload xp[0]
        while (__hip_atomic_load(&prod_cnt[cl * NCHUNKS + 0], __ATOMIC_ACQUIRE,
                                 __HIP_MEMORY_SCOPE_AGENT) < FGROUPS)
            __builtin_amdgcn_s_sleep(8);
        u64 xpbuf[2][4];
        {
            const u64* p = xp_addr(0);
#pragma unroll
            for (int j = 0; j < 4; ++j)
                xpbuf[0][j] = __hip_atomic_load(p + j, __ATOMIC_RELAXED, __HIP_MEMORY_SCOPE_AGENT);
        }

        const int swz = (col & 7) << 4;                // XOR-swizzle: bank spread by read-row
        const int abase = (col << 10) + (quad << 4);   // h[row=col][k = quad*8 + 32*ks]
        float* outp = out + ((size_t)(nb * 16 + quad * 4) * SS) * DD + w * 64 + col;   // layer 3
        float* out2 = out + (size_t)NN * SS * DD
                    + ((size_t)layer * NN + nb * 16 + quad * 4) * DD + w * 64 + col;

        for (int t = 0; t < SS; ++t) {
            const int cur = t & 1;
            // acc init from xp[t] (bias already folded in by producer)
            f32x4 acc[4];
#pragma unroll
            for (int tl = 0; tl < 4; ++tl) {
                const u64 v = xpbuf[cur][tl];
                acc[tl][0] = bf2f((u32)v);
                acc[tl][1] = bf2f((u32)(v >> 16));
                acc[tl][2] = bf2f((u32)(v >> 32));
                acc[tl][3] = bf2f((u32)(v >> 48));
            }
            // chunk boundary: ack chunk c as consumed. Step t-1's closing __syncthreads
            // (vmcnt(0) drain precedes s_barrier) already rendezvoused all waves AFTER
            // each drained its chunk-c prefetch loads, so all of chunk c is in registers.
            // Ack precedes the t+1 poll (nslots=1-safe).
            if ((t & 15) == 15) {
                if (tid == 0)
                    __hip_atomic_store(&cons_done[cl * 32], (u32)((t >> 4) + 1),
                                       __ATOMIC_RELEASE, __HIP_MEMORY_SCOPE_AGENT);
            }
            // prefetch xp[t+1]
            if (t + 1 < SS) {
                if (((t + 1) & 15) == 0) {
                    const int nc = (t + 1) >> 4;
                    while (__hip_atomic_load(&prod_cnt[cl * NCHUNKS + nc], __ATOMIC_ACQUIRE,
                                             __HIP_MEMORY_SCOPE_AGENT) < FGROUPS)
                        __builtin_amdgcn_s_sleep(8);
                }
                const u64* p = xp_addr(t + 1);
#pragma unroll
                for (int j = 0; j < 4; ++j)
                    xpbuf[cur ^ 1][j] =
                        __hip_atomic_load(p + j, __ATOMIC_RELAXED, __HIP_MEMORY_SCOPE_AGENT);
            }
            // recurrent GEMM: A = h[t-1] (LDS buf[t&1], XOR-swizzled), B = Wh (regs + LDS tile 3)
            const char* hrd = lds + HB_OFF + (t & 1) * HB_BYTES;
#pragma unroll
            for (int ks = 0; ks < 16; ++ks) {
                bf16x8 a = *(const bf16x8*)(hrd + ((abase + (ks << 6)) ^ swz));
                acc[0] = __builtin_amdgcn_mfma_f32_16x16x32_bf16(a, whf[ks], acc[0], 0, 0, 0);
                acc[1] = __builtin_amdgcn_mfma_f32_16x16x32_bf16(a, whf[16 + ks], acc[1], 0, 0, 0);
                acc[2] = __builtin_amdgcn_mfma_f32_16x16x32_bf16(a, whf[32 + ks], acc[2], 0, 0, 0);
                bf16x8 b3 = *(const bf16x8*)(whlds + ((size_t)(w * 16 + ks) * 64 + lane) * 8);
                acc[3] = __builtin_amdgcn_mfma_f32_16x16x32_bf16(a, b3, acc[3], 0, 0, 0);
            }
            // NO barrier here: h[t] goes to the OTHER buffer (no WAR vs this step's reads).
            // sigmoid + h[t] publish + outputs
            char* hwrb = lds + HB_OFF + ((t & 1) ^ 1) * HB_BYTES;
#pragma unroll
            for (int tl = 0; tl < 4; ++tl)
#pragma unroll
                for (int i = 0; i < 4; ++i) {
                    const float s = 1.0f / (1.0f + __expf(-acc[tl][i]));
                    const int row = quad * 4 + i;
                    const int boff = ((row << 10) + ((w * 64 + tl * 16 + col) << 1))
                                   ^ ((row & 7) << 4);
                    *(u16*)(hwrb + boff) = f2bf(s);
                    if (layer == 3) outp[((size_t)i * SS + t) * DD + tl * 16] = s;
                    if (t == SS - 1) out2[(size_t)i * DD + tl * 16] = s;
                }
            __syncthreads();   // single per-step barrier: h[t] visible (full drain semantics)
        }
    } else {
        // ========== persistent producers: xp = Wx x + (bx+bh) (round-3-proven) ==========
        const int q = blockIdx.x - NCONS;
        if (q >= NPROD_ACTIVE) return;
        const int combo = q & 31;
        const int cl = combo >> 2, fg = combo & 3;
        const int layer = cl >> 1, nb = cl & 1;
        u16* blds = (u16*)lds;   // Wx B-frags: [ct 8][ks 16][lane 64][8 bf16] = 128 KB

        // stage B = Wx[layer][fg*128 ..+128][512] as bf16 fragments in LDS (once)
        for (int r = 0; r < 16; ++r) {
            const int li = (r * 512 + tid) * 8;
            const int row = li >> 9, k0 = li & 511;
            bf16x8 v = cvt8(Wx + ((size_t)layer * DD + fg * 128 + row) * VV + k0);
            const int ct = row >> 4, fcol = row & 15, ks = k0 >> 5, qd = (k0 >> 3) & 3;
            *(bf16x8*)(blds + ((size_t)((ct * 16 + ks) * 64 + qd * 16 + fcol)) * 8) = v;
        }
        float bias[8];
#pragma unroll
        for (int ct = 0; ct < 8; ++ct) {
            const int f = layer * DD + fg * 128 + ct * 16 + col;
            bias[ct] = bx[f] + bh[f];
        }
        __syncthreads();

        for (int chunk = q >> 5; chunk < NCHUNKS; chunk += CRES) {
            // ---- compute first (ungated) ----
            const int t0 = chunk * CHUNK;
            f32x4 acc[2][8];
#pragma unroll
            for (int rt = 0; rt < 2; ++rt)
#pragma unroll
                for (int ct = 0; ct < 8; ++ct)
                    acc[rt][ct] = f32x4{bias[ct], bias[ct], bias[ct], bias[ct]};
            const float* xr0 = x + ((size_t)(nb * 16 + col) * SS + (t0 + 2 * w)) * VV + quad * 8;
#pragma unroll
            for (int ks = 0; ks < 16; ++ks) {
                bf16x8 a0 = cvt8(xr0 + 32 * ks);
                bf16x8 a1 = cvt8(xr0 + VV + 32 * ks);
#pragma unroll
                for (int ct = 0; ct < 8; ++ct) {
                    bf16x8 b = *(const bf16x8*)(blds + ((size_t)((ct * 16 + ks) * 64 + lane)) * 8);
                    acc[0][ct] = __builtin_amdgcn_mfma_f32_16x16x32_bf16(a0, b, acc[0][ct], 0, 0, 0);
                    acc[1][ct] = __builtin_amdgcn_mfma_f32_16x16x32_bf16(a1, b, acc[1][ct], 0, 0, 0);
                }
            }
            // ---- bounded-buffer gate: slot free when consumer finished chunk - nslots ----
            const int slot = chunk % nslots;
            if (chunk >= nslots && tid == 0) {
                while ((int)__hip_atomic_load(&cons_done[cl * 32], __ATOMIC_ACQUIRE,
                                              __HIP_MEMORY_SCOPE_AGENT) < chunk - nslots + 1)
                    __builtin_amdgcn_s_sleep(16);
            }
            __syncthreads();   // gate known to all waves
            // ---- store in consumer C-frag order: bf16x4 packed u64, agent-scope ----
#pragma unroll
            for (int rt = 0; rt < 2; ++rt) {
                char* base = ring + ((size_t)(slot * NCONS + cl) * CHUNK + (2 * w + rt)) * (8 * 64 * 32);
#pragma unroll
                for (int ct = 0; ct < 8; ++ct) {
                    const int gct = fg * 8 + ct, wc = gct >> 2, tl = gct & 3;
                    const f32x4 a = acc[rt][ct];
                    u64 v = (u64)f2bf(a[0]) | ((u64)f2bf(a[1]) << 16)
                          | ((u64)f2bf(a[2]) << 32) | ((u64)f2bf(a[3]) << 48);
                    __hip_atomic_store((u64*)(base + ((size_t)wc * 64 + lane) * 32 + tl * 8), v,
                                       __ATOMIC_RELAXED, __HIP_MEMORY_SCOPE_AGENT);
                }
            }
            __syncthreads();   // drains all waves' stores (vmcnt0 before s_barrier)
            if (tid == 0)
                __hip_atomic_fetch_add(&prod_cnt[cl * NCHUNKS + chunk], 1u,
                                       __ATOMIC_RELEASE, __HIP_MEMORY_SCOPE_AGENT);
        }
    }
}

extern "C" void kernel_launch(void* const* d_in, const int* in_sizes, int n_in,
                              void* d_out, int out_size, void* d_ws, size_t ws_size,
                              hipStream_t stream) {
    const float* x  = (const float*)d_in[0];
    const float* Wx = (const float*)d_in[1];
    const float* bx = (const float*)d_in[2];
    const float* Wh = (const float*)d_in[3];
    const float* bh = (const float*)d_in[4];
    float* out = (float*)d_out;
    char* ws = (char*)d_ws;

    int nslots = 1;
    if (ws_size > RING_OFF + SLOT_BYTES) {
        size_t n = (ws_size - RING_OFF) / SLOT_BYTES;
        nslots = (int)(n > 8 ? 8 : n);
    }
    hipFuncSetAttribute((const void*)rnn_fused,
                        hipFuncAttributeMaxDynamicSharedMemorySize, LDS_BYTES);
    hipMemsetAsync(ws, 0, RING_OFF, stream);   // zero flags (ws is re-poisoned each call)
    rnn_fused<<<dim3(NBLOCKS), dim3(512), LDS_BYTES, stream>>>(x, Wx, bx, Wh, bh, out, ws, nslots);
}

// Round 5
// 8310.117 us; speedup vs baseline: 7.1703x; 7.1703x over previous
//
#include <hip/hip_runtime.h>

typedef unsigned short u16;
typedef unsigned int u32;
typedef unsigned long long u64;
typedef __attribute__((ext_vector_type(8))) short bf16x8;   // 8 bf16 = 4 VGPRs
typedef __attribute__((ext_vector_type(4))) float f32x4;

#define LL 4
#define NN 32
#define SS 2048
#define VV 512
#define DD 512
#define CHUNK 16
#define NCHUNKS (SS / CHUNK)              // 128
#define PADR 520                           // h row stride (u16): 16B-aligned, odd*16B

#define NCONS 8
#define NBLOCKS 256
#define FGROUPS 4                          // 128 feats per producer combo
#define NCOMBOS 32                         // 8 cl x 4 fg
#define CRES 7                             // chunk residues per combo
#define NPROD_ACTIVE (NCOMBOS * CRES)      // 224 persistent producer blocks

// ws layout
#define PRODCNT_OFF 0                      // u32[8][NCHUNKS]
#define CONSDONE_OFF (NCONS * NCHUNKS * 4) // u32[8], 128B-padded
#define RING_OFF 8192
#define SLOT_BYTES ((size_t)NCONS * CHUNK * 8 * 64 * 32)   // 2 MB: [cl][t][w][lane][32B]

#define LDS_BYTES (131072 + 16 * PADR * 2) // 128K Wh-tile3 / B-stage  +  16.6K h

static __device__ __forceinline__ u16 f2bf(float f) {
    u32 x = __float_as_uint(f);
    x += 0x7fffu + ((x >> 16) & 1u);       // round-to-nearest-even
    return (u16)(x >> 16);
}
static __device__ __forceinline__ float bf2f(u32 h) {
    return __uint_as_float((h & 0xffffu) << 16);
}
static __device__ __forceinline__ bf16x8 cvt8(const float* p) {
    f32x4 a = *(const f32x4*)p;
    f32x4 b = *(const f32x4*)(p + 4);
    bf16x8 r;
    r[0] = (short)f2bf(a[0]); r[1] = (short)f2bf(a[1]);
    r[2] = (short)f2bf(a[2]); r[3] = (short)f2bf(a[3]);
    r[4] = (short)f2bf(b[0]); r[5] = (short)f2bf(b[1]);
    r[6] = (short)f2bf(b[2]); r[7] = (short)f2bf(b[3]);
    return r;
}

// LDS-only barrier: orders LDS reads/writes across waves WITHOUT draining vmcnt,
// so agent-scope xp loads and global out-stores retire across steps instead of
// being force-drained every half-step. sched_barrier(0) guards per rule #18.
static __device__ __forceinline__ void lds_barrier() {
    asm volatile("s_waitcnt lgkmcnt(0)" ::: "memory");
    __builtin_amdgcn_sched_barrier(0);
    __builtin_amdgcn_s_barrier();
    __builtin_amdgcn_sched_barrier(0);
}

__global__ __launch_bounds__(512, 2) void rnn_fused(
    const float* __restrict__ x,   // [N][S][V]
    const float* __restrict__ Wx,  // [L][D][V]
    const float* __restrict__ bx,  // [L][D]
    const float* __restrict__ Wh,  // [L][D][D]
    const float* __restrict__ bh,  // [L][D]
    float* __restrict__ out,       // [N][S][D] ++ [L][N][D]
    char* __restrict__ ws, int nslots)
{
    extern __shared__ __align__(16) char lds[];
    const int tid = threadIdx.x;
    const int lane = tid & 63;
    const int w = tid >> 6;                // wave 0..7
    const int col = lane & 15, quad = lane >> 4;
    u32* prod_cnt = (u32*)(ws + PRODCNT_OFF);    // [cl][chunk]
    u32* cons_done = (u32*)(ws + CONSDONE_OFF);  // [cl*32]
    char* ring = ws + RING_OFF;

    if (blockIdx.x < NCONS) {
        // ========== consumer: the sequential scan (r3-proven structure; PADR h) ==========
        const int cl = blockIdx.x;
        const int layer = cl >> 1, nb = cl & 1;
        u16* whlds = (u16*)lds;                   // [w][ks][lane][8 bf16] = 128 KB (tile 3)
        u16* hb = (u16*)(lds + 131072);           // [16][PADR]

        // Wh: tiles 0..2 -> registers, tile 3 -> LDS
        bf16x8 whf[48];
#pragma unroll
        for (int tl = 0; tl < 3; ++tl)
#pragma unroll
            for (int ks = 0; ks < 16; ++ks)
                whf[tl * 16 + ks] =
                    cvt8(Wh + ((size_t)layer * DD + (w * 64 + tl * 16 + col)) * DD + 32 * ks + quad * 8);
#pragma unroll
        for (int ks = 0; ks < 16; ++ks) {
            bf16x8 f = cvt8(Wh + ((size_t)layer * DD + (w * 64 + 48 + col)) * DD + 32 * ks + quad * 8);
            *(bf16x8*)(whlds + ((size_t)(w * 16 + ks) * 64 + lane) * 8) = f;
        }
        for (int i = tid; i < 16 * PADR; i += 512) hb[i] = 0;   // h[-1] = 0
        __syncthreads();

        auto xp_addr = [&](int t) -> const u64* {
            const int slot = (t >> 4) % nslots;
            return (const u64*)(ring +
                ((((size_t)(slot * NCONS + cl) * CHUNK + (t & 15)) * 8 + w) * 64 + lane) * 32);
        };
        // wait chunk 0, preload xp[0]
        while (__hip_atomic_load(&prod_cnt[cl * NCHUNKS + 0], __ATOMIC_ACQUIRE,
                                 __HIP_MEMORY_SCOPE_AGENT) < FGROUPS)
            __builtin_amdgcn_s_sleep(8);
        u64 xpbuf[2][4];
        {
            const u64* p = xp_addr(0);
#pragma unroll
            for (int j = 0; j < 4; ++j)
                xpbuf[0][j] = __hip_atomic_load(p + j, __ATOMIC_RELAXED, __HIP_MEMORY_SCOPE_AGENT);
        }

        const u16* hrd = hb + col * PADR + quad * 8;
        u16* hwr = hb + (quad * 4) * PADR + w * 64 + col;
        float* outp = out + ((size_t)(nb * 16 + quad * 4) * SS) * DD + w * 64 + col;   // layer 3
        float* out2 = out + (size_t)NN * SS * DD
                    + ((size_t)layer * NN + nb * 16 + quad * 4) * DD + w * 64 + col;

        for (int t = 0; t < SS; ++t) {
            const int cur = t & 1;
            // acc init from xp[t] (bias already folded in by producer)
            f32x4 acc[4];
#pragma unroll
            for (int tl = 0; tl < 4; ++tl) {
                const u64 v = xpbuf[cur][tl];
                acc[tl][0] = bf2f((u32)v);
                acc[tl][1] = bf2f((u32)(v >> 16));
                acc[tl][2] = bf2f((u32)(v >> 32));
                acc[tl][3] = bf2f((u32)(v >> 48));
            }
            // chunk boundary: ack chunk c as consumed. The closing barrier of step
            // t-1 (t-1 = 16c+14) is the FULL __syncthreads below — it drained every
            // wave's chunk-c ring loads (vmcnt(0) precedes s_barrier), so all of
            // chunk c is in registers. Ack precedes the t+1 poll (nslots=1-safe).
            if ((t & 15) == 15) {
                if (tid == 0)
                    __hip_atomic_store(&cons_done[cl * 32], (u32)((t >> 4) + 1),
                                       __ATOMIC_RELEASE, __HIP_MEMORY_SCOPE_AGENT);
            }
            // prefetch xp[t+1]
            if (t + 1 < SS) {
                if (((t + 1) & 15) == 0) {
                    const int nc = (t + 1) >> 4;
                    while (__hip_atomic_load(&prod_cnt[cl * NCHUNKS + nc], __ATOMIC_ACQUIRE,
                                             __HIP_MEMORY_SCOPE_AGENT) < FGROUPS)
                        __builtin_amdgcn_s_sleep(8);
                }
                const u64* p = xp_addr(t + 1);
#pragma unroll
                for (int j = 0; j < 4; ++j)
                    xpbuf[cur ^ 1][j] =
                        __hip_atomic_load(p + j, __ATOMIC_RELAXED, __HIP_MEMORY_SCOPE_AGENT);
            }
            // recurrent GEMM: A = h[t-1] (LDS), B = Wh (regs + LDS tile 3)
#pragma unroll
            for (int ks = 0; ks < 16; ++ks) {
                bf16x8 a = *(const bf16x8*)(hrd + 32 * ks);
                acc[0] = __builtin_amdgcn_mfma_f32_16x16x32_bf16(a, whf[ks], acc[0], 0, 0, 0);
                acc[1] = __builtin_amdgcn_mfma_f32_16x16x32_bf16(a, whf[16 + ks], acc[1], 0, 0, 0);
                acc[2] = __builtin_amdgcn_mfma_f32_16x16x32_bf16(a, whf[32 + ks], acc[2], 0, 0, 0);
                bf16x8 b3 = *(const bf16x8*)(whlds + ((size_t)(w * 16 + ks) * 64 + lane) * 8);
                acc[3] = __builtin_amdgcn_mfma_f32_16x16x32_bf16(a, b3, acc[3], 0, 0, 0);
            }
            lds_barrier();     // barrier 1: all h[t-1] reads done (LDS-only ordering)
            // sigmoid + h[t] publish + outputs
#pragma unroll
            for (int tl = 0; tl < 4; ++tl)
#pragma unroll
                for (int i = 0; i < 4; ++i) {
                    const float s = 1.0f / (1.0f + __expf(-acc[tl][i]));
                    hwr[i * PADR + tl * 16] = f2bf(s);
                    if (layer == 3) outp[((size_t)i * SS + t) * DD + tl * 16] = s;
                    if (t == SS - 1) out2[(size_t)i * DD + tl * 16] = s;
                }
            // barrier 2: h[t] visible. Full drain only once per chunk (end of t%16==14),
            // which is exactly what the t%16==15 ack's correctness argument needs;
            // all other steps use the LDS-only barrier so xp loads / out stores
            // retire across step boundaries instead of being drained every step.
            if ((t & 15) == 14) __syncthreads();
            else                lds_barrier();
        }
    } else {
        // ========== persistent producers: xp = Wx x + (bx+bh) (r3-proven) ==========
        const int q = blockIdx.x - NCONS;
        if (q >= NPROD_ACTIVE) return;
        const int combo = q & 31;
        const int cl = combo >> 2, fg = combo & 3;
        const int layer = cl >> 1, nb = cl & 1;
        u16* blds = (u16*)lds;   // Wx B-frags: [ct 8][ks 16][lane 64][8 bf16] = 128 KB

        // stage B = Wx[layer][fg*128 ..+128][512] as bf16 fragments in LDS (once)
        for (int r = 0; r < 16; ++r) {
            const int li = (r * 512 + tid) * 8;
            const int row = li >> 9, k0 = li & 511;
            bf16x8 v = cvt8(Wx + ((size_t)layer * DD + fg * 128 + row) * VV + k0);
            const int ct = row >> 4, fcol = row & 15, ks = k0 >> 5, qd = (k0 >> 3) & 3;
            *(bf16x8*)(blds + ((size_t)((ct * 16 + ks) * 64 + qd * 16 + fcol)) * 8) = v;
        }
        float bias[8];
#pragma unroll
        for (int ct = 0; ct < 8; ++ct) {
            const int f = layer * DD + fg * 128 + ct * 16 + col;
            bias[ct] = bx[f] + bh[f];
        }
        __syncthreads();

        for (int chunk = q >> 5; chunk < NCHUNKS; chunk += CRES) {
            // ---- compute first (ungated) ----
            const int t0 = chunk * CHUNK;
            f32x4 acc[2][8];
#pragma unroll
            for (int rt = 0; rt < 2; ++rt)
#pragma unroll
                for (int ct = 0; ct < 8; ++ct)
                    acc[rt][ct] = f32x4{bias[ct], bias[ct], bias[ct], bias[ct]};
            const float* xr0 = x + ((size_t)(nb * 16 + col) * SS + (t0 + 2 * w)) * VV + quad * 8;
#pragma unroll
            for (int ks = 0; ks < 16; ++ks) {
                bf16x8 a0 = cvt8(xr0 + 32 * ks);
                bf16x8 a1 = cvt8(xr0 + VV + 32 * ks);
#pragma unroll
                for (int ct = 0; ct < 8; ++ct) {
                    bf16x8 b = *(const bf16x8*)(blds + ((size_t)((ct * 16 + ks) * 64 + lane)) * 8);
                    acc[0][ct] = __builtin_amdgcn_mfma_f32_16x16x32_bf16(a0, b, acc[0][ct], 0, 0, 0);
                    acc[1][ct] = __builtin_amdgcn_mfma_f32_16x16x32_bf16(a1, b, acc[1][ct], 0, 0, 0);
                }
            }
            // ---- bounded-buffer gate. Producers run ~7 chunks (>100 µs) ahead of
            // need, so poll LAZILY: s_sleep(127) ~3.4 µs cuts the agent-acquire storm
            // on the cons_done lines ~8x (it was ~65 same-line MALL atomics/us/line,
            // inflating every consumer xp-load's latency). Wake cost is off-path. ----
            const int slot = chunk % nslots;
            if (chunk >= nslots && tid == 0) {
                while ((int)__hip_atomic_load(&cons_done[cl * 32], __ATOMIC_ACQUIRE,
                                              __HIP_MEMORY_SCOPE_AGENT) < chunk - nslots + 1)
                    __builtin_amdgcn_s_sleep(127);
            }
            __syncthreads();   // gate known to all waves
            // ---- store in consumer C-frag order: bf16x4 packed u64, agent-scope ----
#pragma unroll
            for (int rt = 0; rt < 2; ++rt) {
                char* base = ring + ((size_t)(slot * NCONS + cl) * CHUNK + (2 * w + rt)) * (8 * 64 * 32);
#pragma unroll
                for (int ct = 0; ct < 8; ++ct) {
                    const int gct = fg * 8 + ct, wc = gct >> 2, tl = gct & 3;
                    const f32x4 a = acc[rt][ct];
                    u64 v = (u64)f2bf(a[0]) | ((u64)f2bf(a[1]) << 16)
                          | ((u64)f2bf(a[2]) << 32) | ((u64)f2bf(a[3]) << 48);
                    __hip_atomic_store((u64*)(base + ((size_t)wc * 64 + lane) * 32 + tl * 8), v,
                                       __ATOMIC_RELAXED, __HIP_MEMORY_SCOPE_AGENT);
                }
            }
            __syncthreads();   // drains all waves' stores (vmcnt0 before s_barrier)
            if (tid == 0)
                __hip_atomic_fetch_add(&prod_cnt[cl * NCHUNKS + chunk], 1u,
                                       __ATOMIC_RELEASE, __HIP_MEMORY_SCOPE_AGENT);
        }
    }
}

extern "C" void kernel_launch(void* const* d_in, const int* in_sizes, int n_in,
                              void* d_out, int out_size, void* d_ws, size_t ws_size,
                              hipStream_t stream) {
    const float* x  = (const float*)d_in[0];
    const float* Wx = (const float*)d_in[1];
    const float* bx = (const float*)d_in[2];
    const float* Wh = (const float*)d_in[3];
    const float* bh = (const float*)d_in[4];
    float* out = (float*)d_out;
    char* ws = (char*)d_ws;

    int nslots = 1;
    if (ws_size > RING_OFF + SLOT_BYTES) {
        size_t n = (ws_size - RING_OFF) / SLOT_BYTES;
        nslots = (int)(n > 8 ? 8 : n);
    }
    hipFuncSetAttribute((const void*)rnn_fused,
                        hipFuncAttributeMaxDynamicSharedMemorySize, LDS_BYTES);
    hipMemsetAsync(ws, 0, RING_OFF, stream);   // zero flags (ws is re-poisoned each call)
    rnn_fused<<<dim3(NBLOCKS), dim3(512), LDS_BYTES, stream>>>(x, Wx, bx, Wh, bh, out, ws, nslots);
}

// Round 6
// 7186.066 us; speedup vs baseline: 8.2919x; 1.1564x over previous
//
#include <hip/hip_runtime.h>

typedef unsigned short u16;
typedef unsigned int u32;
typedef unsigned long long u64;
typedef __attribute__((ext_vector_type(8))) short bf16x8;   // 8 bf16 = 4 VGPRs
typedef __attribute__((ext_vector_type(4))) float f32x4;

#define LL 4
#define NN 32
#define SS 2048
#define VV 512
#define DD 512
#define CHUNK 16
#define NCHUNKS (SS / CHUNK)              // 128
#define PADR 520                           // h row stride (u16): 16B-aligned, odd*16B

#define NCONS 8
#define NBLOCKS 256
#define FGROUPS 4                          // 128 feats per producer combo
#define NCOMBOS 32                         // 8 cl x 4 fg
#define CRES 7                             // chunk residues per combo
#define NPROD_ACTIVE (NCOMBOS * CRES)      // 224 persistent producer blocks

// ws layout
#define PRODCNT_OFF 0                      // u32[8][NCHUNKS]
#define CONSDONE_OFF (NCONS * NCHUNKS * 4) // u32[8], 128B-padded
#define RING_OFF 8192
#define SLOT_BYTES ((size_t)NCONS * CHUNK * 8 * 64 * 32)   // 2 MB: [cl][t][w][lane][32B]

#define LDS_BYTES (131072 + 16 * PADR * 2) // 128K Wh-tile3 / B-stage  +  16.6K h

static __device__ __forceinline__ u16 f2bf(float f) {
    u32 x = __float_as_uint(f);
    x += 0x7fffu + ((x >> 16) & 1u);       // round-to-nearest-even
    return (u16)(x >> 16);
}
static __device__ __forceinline__ float bf2f(u32 h) {
    return __uint_as_float((h & 0xffffu) << 16);
}
static __device__ __forceinline__ bf16x8 cvt8(const float* p) {
    f32x4 a = *(const f32x4*)p;
    f32x4 b = *(const f32x4*)(p + 4);
    bf16x8 r;
    r[0] = (short)f2bf(a[0]); r[1] = (short)f2bf(a[1]);
    r[2] = (short)f2bf(a[2]); r[3] = (short)f2bf(a[3]);
    r[4] = (short)f2bf(b[0]); r[5] = (short)f2bf(b[1]);
    r[6] = (short)f2bf(b[2]); r[7] = (short)f2bf(b[3]);
    return r;
}
// sigmoid via raw v_exp_f32/v_rcp_f32 (1-ulp HW ops; saturates correctly at +-inf).
// Without fast-math, __expf + fdiv expand to ~17 VALU ops/element — this is 3.
static __device__ __forceinline__ float sigmoid_fast(float x) {
    const float e = __builtin_amdgcn_exp2f(x * -1.44269504089f);   // exp(-x)
    return __builtin_amdgcn_rcpf(1.0f + e);
}

// LDS-only barrier: orders LDS reads/writes across waves WITHOUT draining vmcnt,
// so agent-scope xp loads and global out-stores retire across steps instead of
// being force-drained every half-step. sched_barrier(0) guards per rule #18.
static __device__ __forceinline__ void lds_barrier() {
    asm volatile("s_waitcnt lgkmcnt(0)" ::: "memory");
    __builtin_amdgcn_sched_barrier(0);
    __builtin_amdgcn_s_barrier();
    __builtin_amdgcn_sched_barrier(0);
}

__global__ __launch_bounds__(512, 2) void rnn_fused(
    const float* __restrict__ x,   // [N][S][V]
    const float* __restrict__ Wx,  // [L][D][V]
    const float* __restrict__ bx,  // [L][D]
    const float* __restrict__ Wh,  // [L][D][D]
    const float* __restrict__ bh,  // [L][D]
    float* __restrict__ out,       // [N][S][D] ++ [L][N][D]
    char* __restrict__ ws, int nslots)
{
    extern __shared__ __align__(16) char lds[];
    const int tid = threadIdx.x;
    const int lane = tid & 63;
    const int w = tid >> 6;                // wave 0..7
    const int col = lane & 15, quad = lane >> 4;
    u32* prod_cnt = (u32*)(ws + PRODCNT_OFF);    // [cl][chunk]
    u32* cons_done = (u32*)(ws + CONSDONE_OFF);  // [cl*32]
    char* ring = ws + RING_OFF;

    if (blockIdx.x < NCONS) {
        // ========== consumer: the sequential scan (r5-proven structure; PADR h) ==========
        const int cl = blockIdx.x;
        const int layer = cl >> 1, nb = cl & 1;
        u16* whlds = (u16*)lds;                   // [w][ks][lane][8 bf16] = 128 KB (tile 3)
        u16* hb = (u16*)(lds + 131072);           // [16][PADR]

        // Wh: tiles 0..2 -> registers, tile 3 -> LDS
        bf16x8 whf[48];
#pragma unroll
        for (int tl = 0; tl < 3; ++tl)
#pragma unroll
            for (int ks = 0; ks < 16; ++ks)
                whf[tl * 16 + ks] =
                    cvt8(Wh + ((size_t)layer * DD + (w * 64 + tl * 16 + col)) * DD + 32 * ks + quad * 8);
#pragma unroll
        for (int ks = 0; ks < 16; ++ks) {
            bf16x8 f = cvt8(Wh + ((size_t)layer * DD + (w * 64 + 48 + col)) * DD + 32 * ks + quad * 8);
            *(bf16x8*)(whlds + ((size_t)(w * 16 + ks) * 64 + lane) * 8) = f;
        }
        for (int i = tid; i < 16 * PADR; i += 512) hb[i] = 0;   // h[-1] = 0
        __syncthreads();

        auto xp_addr = [&](int t) -> const u64* {
            const int slot = (t >> 4) % nslots;
            return (const u64*)(ring +
                ((((size_t)(slot * NCONS + cl) * CHUNK + (t & 15)) * 8 + w) * 64 + lane) * 32);
        };
        // wait chunk 0, preload xp[0]
        while (__hip_atomic_load(&prod_cnt[cl * NCHUNKS + 0], __ATOMIC_ACQUIRE,
                                 __HIP_MEMORY_SCOPE_AGENT) < FGROUPS)
            __builtin_amdgcn_s_sleep(8);
        u64 xpbuf[2][4];
        {
            const u64* p = xp_addr(0);
#pragma unroll
            for (int j = 0; j < 4; ++j)
                xpbuf[0][j] = __hip_atomic_load(p + j, __ATOMIC_RELAXED, __HIP_MEMORY_SCOPE_AGENT);
        }

        const u16* hrd = hb + col * PADR + quad * 8;
        const u16* b3b = whlds + (size_t)w * 16 * 64 * 8;   // wave's tile-3 slice
        u16* hwr = hb + (quad * 4) * PADR + w * 64 + col;
        float* outp = out + ((size_t)(nb * 16 + quad * 4) * SS) * DD + w * 64 + col;   // layer 3
        float* out2 = out + (size_t)NN * SS * DD
                    + ((size_t)layer * NN + nb * 16 + quad * 4) * DD + w * 64 + col;

        for (int t = 0; t < SS; ++t) {
            const int cur = t & 1;
            // chunk boundary FIRST: ack chunk c as consumed. The closing barrier of
            // step t-1 (= 16c+14) was the full __syncthreads — its vmcnt(0) drain
            // guarantees every wave's chunk-c ring loads have landed in REGISTERS,
            // so the producer may overwrite the slot. Ack precedes the poll below
            // (nslots=1-safe).
            if ((t & 15) == 15) {
                if (tid == 0)
                    __hip_atomic_store(&cons_done[cl * 32], (u32)((t >> 4) + 1),
                                       __ATOMIC_RELEASE, __HIP_MEMORY_SCOPE_AGENT);
            }
            // poll + prefetch xp[t+1] as early in the step as possible (max slack)
            if (t + 1 < SS) {
                if (((t + 1) & 15) == 0) {
                    const int nc = (t + 1) >> 4;
                    while (__hip_atomic_load(&prod_cnt[cl * NCHUNKS + nc], __ATOMIC_ACQUIRE,
                                             __HIP_MEMORY_SCOPE_AGENT) < FGROUPS)
                        __builtin_amdgcn_s_sleep(8);
                }
                const u64* p = xp_addr(t + 1);
#pragma unroll
                for (int j = 0; j < 4; ++j)
                    xpbuf[cur ^ 1][j] =
                        __hip_atomic_load(p + j, __ATOMIC_RELAXED, __HIP_MEMORY_SCOPE_AGENT);
            }
            // acc init from xp[t] (bias already folded in by producer)
            f32x4 acc[4];
#pragma unroll
            for (int tl = 0; tl < 4; ++tl) {
                const u64 v = xpbuf[cur][tl];
                acc[tl][0] = bf2f((u32)v);
                acc[tl][1] = bf2f((u32)(v >> 16));
                acc[tl][2] = bf2f((u32)(v >> 32));
                acc[tl][3] = bf2f((u32)(v >> 48));
            }
            // recurrent GEMM: A = h[t-1] (LDS), B = Wh (regs + LDS tile 3).
            // Explicit 2-deep ds_read pipeline with statically-named rotation
            // (rule #20: all indices compile-time after full unroll).
            {
                bf16x8 a0 = *(const bf16x8*)(hrd);
                bf16x8 b0 = *(const bf16x8*)(b3b + lane * 8);
                bf16x8 a1 = *(const bf16x8*)(hrd + 32);
                bf16x8 b1 = *(const bf16x8*)(b3b + 512 + lane * 8);
#pragma unroll
                for (int ks = 0; ks < 16; ++ks) {
                    bf16x8 an = a1, bn = b1;
                    if (ks < 14) {
                        an = *(const bf16x8*)(hrd + 32 * (ks + 2));
                        bn = *(const bf16x8*)(b3b + 512 * (ks + 2) + lane * 8);
                    }
                    acc[0] = __builtin_amdgcn_mfma_f32_16x16x32_bf16(a0, whf[ks], acc[0], 0, 0, 0);
                    acc[1] = __builtin_amdgcn_mfma_f32_16x16x32_bf16(a0, whf[16 + ks], acc[1], 0, 0, 0);
                    acc[2] = __builtin_amdgcn_mfma_f32_16x16x32_bf16(a0, whf[32 + ks], acc[2], 0, 0, 0);
                    acc[3] = __builtin_amdgcn_mfma_f32_16x16x32_bf16(a0, b0, acc[3], 0, 0, 0);
                    a0 = a1; b0 = b1; a1 = an; b1 = bn;
                }
            }
            lds_barrier();     // barrier 1: all h[t-1] reads done (LDS-only ordering)
            // sigmoid + h[t] publish + outputs (out-stores retire across steps)
#pragma unroll
            for (int tl = 0; tl < 4; ++tl)
#pragma unroll
                for (int i = 0; i < 4; ++i) {
                    const float s = sigmoid_fast(acc[tl][i]);
                    hwr[i * PADR + tl * 16] = f2bf(s);
                    if (layer == 3) outp[((size_t)i * SS + t) * DD + tl * 16] = s;
                    if (t == SS - 1) out2[(size_t)i * DD + tl * 16] = s;
                }
            // barrier 2: h[t] visible. Full drain only once per chunk (end of t%16==14)
            // — exactly what the t%16==15 ack's correctness argument needs; all other
            // steps are LDS-only so xp loads / out stores fly across step boundaries.
            if ((t & 15) == 14) __syncthreads();
            else                lds_barrier();
        }
    } else {
        // ========== persistent producers: xp = Wx x + (bx+bh) (r3/r5-proven) ==========
        const int q = blockIdx.x - NCONS;
        if (q >= NPROD_ACTIVE) return;
        const int combo = q & 31;
        const int cl = combo >> 2, fg = combo & 3;
        const int layer = cl >> 1, nb = cl & 1;
        u16* blds = (u16*)lds;   // Wx B-frags: [ct 8][ks 16][lane 64][8 bf16] = 128 KB

        // stage B = Wx[layer][fg*128 ..+128][512] as bf16 fragments in LDS (once)
        for (int r = 0; r < 16; ++r) {
            const int li = (r * 512 + tid) * 8;
            const int row = li >> 9, k0 = li & 511;
            bf16x8 v = cvt8(Wx + ((size_t)layer * DD + fg * 128 + row) * VV + k0);
            const int ct = row >> 4, fcol = row & 15, ks = k0 >> 5, qd = (k0 >> 3) & 3;
            *(bf16x8*)(blds + ((size_t)((ct * 16 + ks) * 64 + qd * 16 + fcol)) * 8) = v;
        }
        float bias[8];
#pragma unroll
        for (int ct = 0; ct < 8; ++ct) {
            const int f = layer * DD + fg * 128 + ct * 16 + col;
            bias[ct] = bx[f] + bh[f];
        }
        __syncthreads();

        for (int chunk = q >> 5; chunk < NCHUNKS; chunk += CRES) {
            // ---- compute first (ungated) ----
            const int t0 = chunk * CHUNK;
            f32x4 acc[2][8];
#pragma unroll
            for (int rt = 0; rt < 2; ++rt)
#pragma unroll
                for (int ct = 0; ct < 8; ++ct)
                    acc[rt][ct] = f32x4{bias[ct], bias[ct], bias[ct], bias[ct]};
            const float* xr0 = x + ((size_t)(nb * 16 + col) * SS + (t0 + 2 * w)) * VV + quad * 8;
#pragma unroll
            for (int ks = 0; ks < 16; ++ks) {
                bf16x8 a0 = cvt8(xr0 + 32 * ks);
                bf16x8 a1 = cvt8(xr0 + VV + 32 * ks);
#pragma unroll
                for (int ct = 0; ct < 8; ++ct) {
                    bf16x8 b = *(const bf16x8*)(blds + ((size_t)((ct * 16 + ks) * 64 + lane)) * 8);
                    acc[0][ct] = __builtin_amdgcn_mfma_f32_16x16x32_bf16(a0, b, acc[0][ct], 0, 0, 0);
                    acc[1][ct] = __builtin_amdgcn_mfma_f32_16x16x32_bf16(a1, b, acc[1][ct], 0, 0, 0);
                }
            }
            // ---- bounded-buffer gate: lazy poll (s_sleep 127 ~3.4 us) — producers
            // run ~7 chunks ahead, so the wake latency is off the critical path and
            // the agent-acquire storm on the cons_done lines stays ~8x reduced. ----
            const int slot = chunk % nslots;
            if (chunk >= nslots && tid == 0) {
                while ((int)__hip_atomic_load(&cons_done[cl * 32], __ATOMIC_ACQUIRE,
                                              __HIP_MEMORY_SCOPE_AGENT) < chunk - nslots + 1)
                    __builtin_amdgcn_s_sleep(127);
            }
            __syncthreads();   // gate known to all waves
            // ---- store in consumer C-frag order: bf16x4 packed u64, agent-scope ----
#pragma unroll
            for (int rt = 0; rt < 2; ++rt) {
                char* base = ring + ((size_t)(slot * NCONS + cl) * CHUNK + (2 * w + rt)) * (8 * 64 * 32);
#pragma unroll
                for (int ct = 0; ct < 8; ++ct) {
                    const int gct = fg * 8 + ct, wc = gct >> 2, tl = gct & 3;
                    const f32x4 a = acc[rt][ct];
                    u64 v = (u64)f2bf(a[0]) | ((u64)f2bf(a[1]) << 16)
                          | ((u64)f2bf(a[2]) << 32) | ((u64)f2bf(a[3]) << 48);
                    __hip_atomic_store((u64*)(base + ((size_t)wc * 64 + lane) * 32 + tl * 8), v,
                                       __ATOMIC_RELAXED, __HIP_MEMORY_SCOPE_AGENT);
                }
            }
            __syncthreads();   // drains all waves' stores (vmcnt0 before s_barrier)
            if (tid == 0)
                __hip_atomic_fetch_add(&prod_cnt[cl * NCHUNKS + chunk], 1u,
                                       __ATOMIC_RELEASE, __HIP_MEMORY_SCOPE_AGENT);
        }
    }
}

extern "C" void kernel_launch(void* const* d_in, const int* in_sizes, int n_in,
                              void* d_out, int out_size, void* d_ws, size_t ws_size,
                              hipStream_t stream) {
    const float* x  = (const float*)d_in[0];
    const float* Wx = (const float*)d_in[1];
    const float* bx = (const float*)d_in[2];
    const float* Wh = (const float*)d_in[3];
    const float* bh = (const float*)d_in[4];
    float* out = (float*)d_out;
    char* ws = (char*)d_ws;

    int nslots = 1;
    if (ws_size > RING_OFF + SLOT_BYTES) {
        size_t n = (ws_size - RING_OFF) / SLOT_BYTES;
        nslots = (int)(n > 8 ? 8 : n);
    }
    hipFuncSetAttribute((const void*)rnn_fused,
                        hipFuncAttributeMaxDynamicSharedMemorySize, LDS_BYTES);
    hipMemsetAsync(ws, 0, RING_OFF, stream);   // zero flags (ws is re-poisoned each call)
    rnn_fused<<<dim3(NBLOCKS), dim3(512), LDS_BYTES, stream>>>(x, Wx, bx, Wh, bh, out, ws, nslots);
}

// Round 7
// 6814.662 us; speedup vs baseline: 8.7438x; 1.0545x over previous
//
#include <hip/hip_runtime.h>

typedef unsigned short u16;
typedef unsigned int u32;
typedef unsigned long long u64;
typedef __attribute__((ext_vector_type(8))) short bf16x8;   // 8 bf16 = 4 VGPRs
typedef __attribute__((ext_vector_type(4))) float f32x4;

#define LL 4
#define NN 32
#define SS 2048
#define VV 512
#define DD 512
#define CHUNK 16
#define NCHUNKS (SS / CHUNK)              // 128
#define PADR 520                           // h row stride (u16): 8B-aligned rows (1040 B)

#define NCONS 8
#define NBLOCKS 256
#define FGROUPS 4                          // 128 feats per producer combo
#define NCOMBOS 32                         // 8 cl x 4 fg
#define CRES 7                             // chunk residues per combo
#define NPROD_ACTIVE (NCOMBOS * CRES)      // 224 persistent producer blocks

// ws layout
#define PRODCNT_OFF 0                      // u32[8][NCHUNKS]
#define CONSDONE_OFF (NCONS * NCHUNKS * 4) // u32[8], 128B-padded
#define RING_OFF 8192
#define SLOT_BYTES ((size_t)NCONS * CHUNK * 8 * 64 * 32)   // 2 MB: [cl][t][w][lane][32B]

#define LDS_BYTES (131072 + 16 * PADR * 2) // 128K Wh-tile3 / B-stage  +  16.6K h

static __device__ __forceinline__ u16 f2bf(float f) {
    u32 x = __float_as_uint(f);
    x += 0x7fffu + ((x >> 16) & 1u);       // round-to-nearest-even
    return (u16)(x >> 16);
}
static __device__ __forceinline__ float bf2f(u32 h) {
    return __uint_as_float((h & 0xffffu) << 16);
}
static __device__ __forceinline__ bf16x8 cvt8(const float* p) {
    f32x4 a = *(const f32x4*)p;
    f32x4 b = *(const f32x4*)(p + 4);
    bf16x8 r;
    r[0] = (short)f2bf(a[0]); r[1] = (short)f2bf(a[1]);
    r[2] = (short)f2bf(a[2]); r[3] = (short)f2bf(a[3]);
    r[4] = (short)f2bf(b[0]); r[5] = (short)f2bf(b[1]);
    r[6] = (short)f2bf(b[2]); r[7] = (short)f2bf(b[3]);
    return r;
}
// sigma-permuted K-gather for consumer B-fragments. h is stored with each wave's
// 64-feat block permuted: stored s = w*64 + col*4 + tl for true feat
// f = w*64 + tl*16 + col (enables packed b64 h-writes). The B-frag K-element j
// must follow the same map: trueK = (ks>>1)*64 + (j&3)*16 + (ks&1)*8 + quad*2 + (j>>2).
// Elements j and j+4 are memory-adjacent -> 4x float2 loads.
static __device__ __forceinline__ bf16x8 gather8(const float* Wrow, int ks, int quad) {
    const int base = (ks >> 1) * 64 + (ks & 1) * 8 + quad * 2;
    bf16x8 r;
#pragma unroll
    for (int jj = 0; jj < 4; ++jj) {
        const float2 v = *(const float2*)(Wrow + base + jj * 16);
        r[jj]     = (short)f2bf(v.x);
        r[jj + 4] = (short)f2bf(v.y);
    }
    return r;
}
// sigmoid via raw v_exp_f32/v_rcp_f32 (1-ulp HW ops; saturates correctly at +-inf).
static __device__ __forceinline__ float sigmoid_fast(float x) {
    const float e = __builtin_amdgcn_exp2f(x * -1.44269504089f);   // exp(-x)
    return __builtin_amdgcn_rcpf(1.0f + e);
}

// LDS-only barrier: orders LDS reads/writes across waves WITHOUT draining vmcnt,
// so agent-scope xp loads and global out-stores retire across steps instead of
// being force-drained every half-step. sched_barrier(0) guards per rule #18.
static __device__ __forceinline__ void lds_barrier() {
    asm volatile("s_waitcnt lgkmcnt(0)" ::: "memory");
    __builtin_amdgcn_sched_barrier(0);
    __builtin_amdgcn_s_barrier();
    __builtin_amdgcn_sched_barrier(0);
}

__global__ __launch_bounds__(512, 2) void rnn_fused(
    const float* __restrict__ x,   // [N][S][V]
    const float* __restrict__ Wx,  // [L][D][V]
    const float* __restrict__ bx,  // [L][D]
    const float* __restrict__ Wh,  // [L][D][D]
    const float* __restrict__ bh,  // [L][D]
    float* __restrict__ out,       // [N][S][D] ++ [L][N][D]
    char* __restrict__ ws, int nslots)
{
    extern __shared__ __align__(16) char lds[];
    const int tid = threadIdx.x;
    const int lane = tid & 63;
    const int w = tid >> 6;                // wave 0..7
    const int col = lane & 15, quad = lane >> 4;
    u32* prod_cnt = (u32*)(ws + PRODCNT_OFF);    // [cl][chunk]
    u32* cons_done = (u32*)(ws + CONSDONE_OFF);  // [cl*32]
    char* ring = ws + RING_OFF;

    if (blockIdx.x < NCONS) {
        // ========== consumer: the sequential scan (r6 structure + sigma-packed h) ==========
        const int cl = blockIdx.x;
        const int layer = cl >> 1, nb = cl & 1;
        u16* whlds = (u16*)lds;                   // [w][ks][lane][8 bf16] = 128 KB (tile 3)
        u16* hb = (u16*)(lds + 131072);           // [16][PADR], sigma-permuted feat order

        // Wh: tiles 0..2 -> registers, tile 3 -> LDS (K-elements sigma-gathered)
        bf16x8 whf[48];
#pragma unroll
        for (int tl = 0; tl < 3; ++tl)
#pragma unroll
            for (int ks = 0; ks < 16; ++ks)
                whf[tl * 16 + ks] =
                    gather8(Wh + ((size_t)layer * DD + (w * 64 + tl * 16 + col)) * DD, ks, quad);
#pragma unroll
        for (int ks = 0; ks < 16; ++ks) {
            bf16x8 f = gather8(Wh + ((size_t)layer * DD + (w * 64 + 48 + col)) * DD, ks, quad);
            *(bf16x8*)(whlds + ((size_t)(w * 16 + ks) * 64 + lane) * 8) = f;
        }
        for (int i = tid; i < 16 * PADR; i += 512) hb[i] = 0;   // h[-1] = 0
        __syncthreads();

        auto xp_addr = [&](int t) -> const u64* {
            const int slot = (t >> 4) % nslots;
            return (const u64*)(ring +
                ((((size_t)(slot * NCONS + cl) * CHUNK + (t & 15)) * 8 + w) * 64 + lane) * 32);
        };
        // wait chunk 0, preload xp[0]
        while (__hip_atomic_load(&prod_cnt[cl * NCHUNKS + 0], __ATOMIC_ACQUIRE,
                                 __HIP_MEMORY_SCOPE_AGENT) < FGROUPS)
            __builtin_amdgcn_s_sleep(8);
        u64 xpbuf[2][4];
        {
            const u64* p = xp_addr(0);
#pragma unroll
            for (int j = 0; j < 4; ++j)
                xpbuf[0][j] = __hip_atomic_load(p + j, __ATOMIC_RELAXED, __HIP_MEMORY_SCOPE_AGENT);
        }

        const u16* hrd = hb + col * PADR + quad * 8;        // A-read: unchanged addresses
        const u16* b3b = whlds + (size_t)w * 16 * 64 * 8;   // wave's tile-3 slice
        u16* hwr = hb + (quad * 4) * PADR + w * 64 + col * 4;  // sigma-packed write base
        float* outp = out + ((size_t)(nb * 16 + quad * 4) * SS) * DD + w * 64 + col;   // layer 3
        float* out2 = out + (size_t)NN * SS * DD
                    + ((size_t)layer * NN + nb * 16 + quad * 4) * DD + w * 64 + col;

        for (int t = 0; t < SS; ++t) {
            const int cur = t & 1;
            // chunk boundary FIRST: ack chunk c as consumed. The closing barrier of
            // step t-1 (= 16c+14) was the full __syncthreads — its vmcnt(0) drain
            // retired every wave's chunk-c ring loads into registers, so the
            // producer may overwrite the slot. Ack precedes the poll (nslots=1-safe).
            if ((t & 15) == 15) {
                if (tid == 0)
                    __hip_atomic_store(&cons_done[cl * 32], (u32)((t >> 4) + 1),
                                       __ATOMIC_RELEASE, __HIP_MEMORY_SCOPE_AGENT);
            }
            // poll + prefetch xp[t+1] as early in the step as possible (max slack)
            if (t + 1 < SS) {
                if (((t + 1) & 15) == 0) {
                    const int nc = (t + 1) >> 4;
                    while (__hip_atomic_load(&prod_cnt[cl * NCHUNKS + nc], __ATOMIC_ACQUIRE,
                                             __HIP_MEMORY_SCOPE_AGENT) < FGROUPS)
                        __builtin_amdgcn_s_sleep(8);
                }
                const u64* p = xp_addr(t + 1);
#pragma unroll
                for (int j = 0; j < 4; ++j)
                    xpbuf[cur ^ 1][j] =
                        __hip_atomic_load(p + j, __ATOMIC_RELAXED, __HIP_MEMORY_SCOPE_AGENT);
            }
            // acc init from xp[t] (bias already folded in by producer)
            f32x4 acc[4];
#pragma unroll
            for (int tl = 0; tl < 4; ++tl) {
                const u64 v = xpbuf[cur][tl];
                acc[tl][0] = bf2f((u32)v);
                acc[tl][1] = bf2f((u32)(v >> 16));
                acc[tl][2] = bf2f((u32)(v >> 32));
                acc[tl][3] = bf2f((u32)(v >> 48));
            }
            // recurrent GEMM: A = h[t-1] (LDS), B = Wh (regs + LDS tile 3).
            // A 2-deep, B3 3-deep ds_read pipeline (B3 depends on nothing in-step);
            // statically-named rotation (rule #20: compile-time indices after unroll).
            {
                bf16x8 a0 = *(const bf16x8*)(hrd);
                bf16x8 a1 = *(const bf16x8*)(hrd + 32);
                bf16x8 b0 = *(const bf16x8*)(b3b + lane * 8);
                bf16x8 b1 = *(const bf16x8*)(b3b + 512 + lane * 8);
                bf16x8 b2 = *(const bf16x8*)(b3b + 1024 + lane * 8);
#pragma unroll
                for (int ks = 0; ks < 16; ++ks) {
                    bf16x8 an = a1, bn = b2;
                    if (ks < 14) an = *(const bf16x8*)(hrd + 32 * (ks + 2));
                    if (ks < 13) bn = *(const bf16x8*)(b3b + 512 * (ks + 3) + lane * 8);
                    acc[0] = __builtin_amdgcn_mfma_f32_16x16x32_bf16(a0, whf[ks], acc[0], 0, 0, 0);
                    acc[1] = __builtin_amdgcn_mfma_f32_16x16x32_bf16(a0, whf[16 + ks], acc[1], 0, 0, 0);
                    acc[2] = __builtin_amdgcn_mfma_f32_16x16x32_bf16(a0, whf[32 + ks], acc[2], 0, 0, 0);
                    acc[3] = __builtin_amdgcn_mfma_f32_16x16x32_bf16(a0, b0, acc[3], 0, 0, 0);
                    a0 = a1; a1 = an;
                    b0 = b1; b1 = b2; b2 = bn;
                }
            }
            lds_barrier();     // barrier 1: all h[t-1] reads done (LDS-only ordering)
            // sigmoid + sigma-packed h[t] publish (4 x ds_write_b64, conflict-free)
            // + global outputs (retire across steps)
#pragma unroll
            for (int i = 0; i < 4; ++i) {
                const float s0 = sigmoid_fast(acc[0][i]);
                const float s1 = sigmoid_fast(acc[1][i]);
                const float s2 = sigmoid_fast(acc[2][i]);
                const float s3 = sigmoid_fast(acc[3][i]);
                const u64 pk = (u64)f2bf(s0) | ((u64)f2bf(s1) << 16)
                             | ((u64)f2bf(s2) << 32) | ((u64)f2bf(s3) << 48);
                *(u64*)(hwr + (size_t)i * PADR) = pk;          // stored s = w*64+col*4+{0..3}
                if (layer == 3) {
                    float* o = outp + ((size_t)i * SS + t) * DD;
                    o[0] = s0; o[16] = s1; o[32] = s2; o[48] = s3;
                }
                if (t == SS - 1) {
                    float* o2 = out2 + (size_t)i * DD;
                    o2[0] = s0; o2[16] = s1; o2[32] = s2; o2[48] = s3;
                }
            }
            // barrier 2: h[t] visible. Full drain once per chunk (end of t%16==14) —
            // exactly what the t%16==15 ack's correctness argument needs; all other
            // steps are LDS-only so xp loads / out stores fly across step boundaries.
            if ((t & 15) == 14) __syncthreads();
            else                lds_barrier();
        }
    } else {
        // ========== persistent producers: xp = Wx x + (bx+bh) (r3/r5-proven, untouched) ==========
        const int q = blockIdx.x - NCONS;
        if (q >= NPROD_ACTIVE) return;
        const int combo = q & 31;
        const int cl = combo >> 2, fg = combo & 3;
        const int layer = cl >> 1, nb = cl & 1;
        u16* blds = (u16*)lds;   // Wx B-frags: [ct 8][ks 16][lane 64][8 bf16] = 128 KB

        // stage B = Wx[layer][fg*128 ..+128][512] as bf16 fragments in LDS (once)
        for (int r = 0; r < 16; ++r) {
            const int li = (r * 512 + tid) * 8;
            const int row = li >> 9, k0 = li & 511;
            bf16x8 v = cvt8(Wx + ((size_t)layer * DD + fg * 128 + row) * VV + k0);
            const int ct = row >> 4, fcol = row & 15, ks = k0 >> 5, qd = (k0 >> 3) & 3;
            *(bf16x8*)(blds + ((size_t)((ct * 16 + ks) * 64 + qd * 16 + fcol)) * 8) = v;
        }
        float bias[8];
#pragma unroll
        for (int ct = 0; ct < 8; ++ct) {
            const int f = layer * DD + fg * 128 + ct * 16 + col;
            bias[ct] = bx[f] + bh[f];
        }
        __syncthreads();

        for (int chunk = q >> 5; chunk < NCHUNKS; chunk += CRES) {
            // ---- compute first (ungated) ----
            const int t0 = chunk * CHUNK;
            f32x4 acc[2][8];
#pragma unroll
            for (int rt = 0; rt < 2; ++rt)
#pragma unroll
                for (int ct = 0; ct < 8; ++ct)
                    acc[rt][ct] = f32x4{bias[ct], bias[ct], bias[ct], bias[ct]};
            const float* xr0 = x + ((size_t)(nb * 16 + col) * SS + (t0 + 2 * w)) * VV + quad * 8;
#pragma unroll
            for (int ks = 0; ks < 16; ++ks) {
                bf16x8 a0 = cvt8(xr0 + 32 * ks);
                bf16x8 a1 = cvt8(xr0 + VV + 32 * ks);
#pragma unroll
                for (int ct = 0; ct < 8; ++ct) {
                    bf16x8 b = *(const bf16x8*)(blds + ((size_t)((ct * 16 + ks) * 64 + lane)) * 8);
                    acc[0][ct] = __builtin_amdgcn_mfma_f32_16x16x32_bf16(a0, b, acc[0][ct], 0, 0, 0);
                    acc[1][ct] = __builtin_amdgcn_mfma_f32_16x16x32_bf16(a1, b, acc[1][ct], 0, 0, 0);
                }
            }
            // ---- bounded-buffer gate: lazy poll (s_sleep 127 ~3.4 us) — producers
            // run ~7 chunks ahead, so wake latency is off-path and the agent-acquire
            // storm on the cons_done lines stays ~8x reduced. ----
            const int slot = chunk % nslots;
            if (chunk >= nslots && tid == 0) {
                while ((int)__hip_atomic_load(&cons_done[cl * 32], __ATOMIC_ACQUIRE,
                                              __HIP_MEMORY_SCOPE_AGENT) < chunk - nslots + 1)
                    __builtin_amdgcn_s_sleep(127);
            }
            __syncthreads();   // gate known to all waves
            // ---- store in consumer C-frag order: bf16x4 packed u64, agent-scope ----
#pragma unroll
            for (int rt = 0; rt < 2; ++rt) {
                char* base = ring + ((size_t)(slot * NCONS + cl) * CHUNK + (2 * w + rt)) * (8 * 64 * 32);
#pragma unroll
                for (int ct = 0; ct < 8; ++ct) {
                    const int gct = fg * 8 + ct, wc = gct >> 2, tl = gct & 3;
                    const f32x4 a = acc[rt][ct];
                    u64 v = (u64)f2bf(a[0]) | ((u64)f2bf(a[1]) << 16)
                          | ((u64)f2bf(a[2]) << 32) | ((u64)f2bf(a[3]) << 48);
                    __hip_atomic_store((u64*)(base + ((size_t)wc * 64 + lane) * 32 + tl * 8), v,
                                       __ATOMIC_RELAXED, __HIP_MEMORY_SCOPE_AGENT);
                }
            }
            __syncthreads();   // drains all waves' stores (vmcnt0 before s_barrier)
            if (tid == 0)
                __hip_atomic_fetch_add(&prod_cnt[cl * NCHUNKS + chunk], 1u,
                                       __ATOMIC_RELEASE, __HIP_MEMORY_SCOPE_AGENT);
        }
    }
}

extern "C" void kernel_launch(void* const* d_in, const int* in_sizes, int n_in,
                              void* d_out, int out_size, void* d_ws, size_t ws_size,
                              hipStream_t stream) {
    const float* x  = (const float*)d_in[0];
    const float* Wx = (const float*)d_in[1];
    const float* bx = (const float*)d_in[2];
    const float* Wh = (const float*)d_in[3];
    const float* bh = (const float*)d_in[4];
    float* out = (float*)d_out;
    char* ws = (char*)d_ws;

    int nslots = 1;
    if (ws_size > RING_OFF + SLOT_BYTES) {
        size_t n = (ws_size - RING_OFF) / SLOT_BYTES;
        nslots = (int)(n > 8 ? 8 : n);
    }
    hipFuncSetAttribute((const void*)rnn_fused,
                        hipFuncAttributeMaxDynamicSharedMemorySize, LDS_BYTES);
    hipMemsetAsync(ws, 0, RING_OFF, stream);   // zero flags (ws is re-poisoned each call)
    rnn_fused<<<dim3(NBLOCKS), dim3(512), LDS_BYTES, stream>>>(x, Wx, bx, Wh, bh, out, ws, nslots);
}

// Round 8
// 6656.088 us; speedup vs baseline: 8.9521x; 1.0238x over previous
//
#include <hip/hip_runtime.h>

typedef unsigned short u16;
typedef unsigned int u32;
typedef unsigned long long u64;
typedef __attribute__((ext_vector_type(8))) short bf16x8;   // 8 bf16 = 4 VGPRs
typedef __attribute__((ext_vector_type(4))) float f32x4;

#define LL 4
#define NN 32
#define SS 2048
#define VV 512
#define DD 512
#define CHUNK 16
#define NCHUNKS (SS / CHUNK)              // 128
#define PADR 520                           // h row stride (u16): 8B-aligned rows (1040 B)

#define NCONS 8
#define NBLOCKS 256
#define FGROUPS 4                          // 128 feats per producer combo
#define NCOMBOS 32                         // 8 cl x 4 fg
#define CRES 7                             // chunk residues per combo
#define NPROD_ACTIVE (NCOMBOS * CRES)      // 224 persistent producer blocks

// ws layout
#define PRODCNT_OFF 0                      // u32[8][NCHUNKS]
#define CONSDONE_OFF (NCONS * NCHUNKS * 4) // u32[8], 128B-padded
#define RING_OFF 8192
#define SLOT_BYTES ((size_t)NCONS * CHUNK * 8 * 64 * 32)   // 2 MB: [cl][t][w][lane][32B]

#define LDS_BYTES (131072 + 16 * PADR * 2) // 128K Wh-tile3 / B-stage  +  16.6K h

static __device__ __forceinline__ u16 f2bf(float f) {
    u32 x = __float_as_uint(f);
    x += 0x7fffu + ((x >> 16) & 1u);       // round-to-nearest-even
    return (u16)(x >> 16);
}
static __device__ __forceinline__ float bf2f(u32 h) {
    return __uint_as_float((h & 0xffffu) << 16);
}
static __device__ __forceinline__ bf16x8 cvt8(const float* p) {
    f32x4 a = *(const f32x4*)p;
    f32x4 b = *(const f32x4*)(p + 4);
    bf16x8 r;
    r[0] = (short)f2bf(a[0]); r[1] = (short)f2bf(a[1]);
    r[2] = (short)f2bf(a[2]); r[3] = (short)f2bf(a[3]);
    r[4] = (short)f2bf(b[0]); r[5] = (short)f2bf(b[1]);
    r[6] = (short)f2bf(b[2]); r[7] = (short)f2bf(b[3]);
    return r;
}
// sigma-permuted K-gather for consumer B-fragments. h is stored with each wave's
// 64-feat block permuted: stored s = w*64 + col*4 + tl for true feat
// f = w*64 + tl*16 + col (enables packed b64 h-writes). The B-frag K-element j
// must follow the same map: trueK = (ks>>1)*64 + (j&3)*16 + (ks&1)*8 + quad*2 + (j>>2).
// Elements j and j+4 are memory-adjacent -> 4x float2 loads.
static __device__ __forceinline__ bf16x8 gather8(const float* Wrow, int ks, int quad) {
    const int base = (ks >> 1) * 64 + (ks & 1) * 8 + quad * 2;
    bf16x8 r;
#pragma unroll
    for (int jj = 0; jj < 4; ++jj) {
        const float2 v = *(const float2*)(Wrow + base + jj * 16);
        r[jj]     = (short)f2bf(v.x);
        r[jj + 4] = (short)f2bf(v.y);
    }
    return r;
}
// sigmoid via raw v_exp_f32/v_rcp_f32 (1-ulp HW ops; saturates correctly at +-inf).
static __device__ __forceinline__ float sigmoid_fast(float x) {
    const float e = __builtin_amdgcn_exp2f(x * -1.44269504089f);   // exp(-x)
    return __builtin_amdgcn_rcpf(1.0f + e);
}

// LDS-only barrier: orders LDS reads/writes across waves WITHOUT draining vmcnt,
// so agent-scope xp loads and global out-stores retire across steps instead of
// being force-drained every half-step. sched_barrier(0) guards per rule #18.
static __device__ __forceinline__ void lds_barrier() {
    asm volatile("s_waitcnt lgkmcnt(0)" ::: "memory");
    __builtin_amdgcn_sched_barrier(0);
    __builtin_amdgcn_s_barrier();
    __builtin_amdgcn_sched_barrier(0);
}

__global__ __launch_bounds__(512, 2) void rnn_fused(
    const float* __restrict__ x,   // [N][S][V]
    const float* __restrict__ Wx,  // [L][D][V]
    const float* __restrict__ bx,  // [L][D]
    const float* __restrict__ Wh,  // [L][D][D]
    const float* __restrict__ bh,  // [L][D]
    float* __restrict__ out,       // [N][S][D] ++ [L][N][D]
    char* __restrict__ ws, int nslots)
{
    extern __shared__ __align__(16) char lds[];
    const int tid = threadIdx.x;
    const int lane = tid & 63;
    const int w = tid >> 6;                // wave 0..7
    const int col = lane & 15, quad = lane >> 4;
    u32* prod_cnt = (u32*)(ws + PRODCNT_OFF);    // [cl][chunk]
    u32* cons_done = (u32*)(ws + CONSDONE_OFF);  // [cl*32]
    char* ring = ws + RING_OFF;

    if (blockIdx.x < NCONS) {
        // ========== consumer: sequential scan (r7 structure + deep ds_read pipeline) ==========
        const int cl = blockIdx.x;
        const int layer = cl >> 1, nb = cl & 1;
        u16* whlds = (u16*)lds;                   // [w][ks][lane][8 bf16] = 128 KB (tile 3)
        u16* hb = (u16*)(lds + 131072);           // [16][PADR], sigma-permuted feat order

        // Wh: tiles 0..2 -> registers, tile 3 -> LDS (K-elements sigma-gathered)
        bf16x8 whf[48];
#pragma unroll
        for (int tl = 0; tl < 3; ++tl)
#pragma unroll
            for (int ks = 0; ks < 16; ++ks)
                whf[tl * 16 + ks] =
                    gather8(Wh + ((size_t)layer * DD + (w * 64 + tl * 16 + col)) * DD, ks, quad);
#pragma unroll
        for (int ks = 0; ks < 16; ++ks) {
            bf16x8 f = gather8(Wh + ((size_t)layer * DD + (w * 64 + 48 + col)) * DD, ks, quad);
            *(bf16x8*)(whlds + ((size_t)(w * 16 + ks) * 64 + lane) * 8) = f;
        }
        for (int i = tid; i < 16 * PADR; i += 512) hb[i] = 0;   // h[-1] = 0
        __syncthreads();

        auto xp_addr = [&](int t) -> const u64* {
            const int slot = (t >> 4) % nslots;
            return (const u64*)(ring +
                ((((size_t)(slot * NCONS + cl) * CHUNK + (t & 15)) * 8 + w) * 64 + lane) * 32);
        };
        // wait chunk 0, preload xp[0]
        while (__hip_atomic_load(&prod_cnt[cl * NCHUNKS + 0], __ATOMIC_ACQUIRE,
                                 __HIP_MEMORY_SCOPE_AGENT) < FGROUPS)
            __builtin_amdgcn_s_sleep(8);
        u64 xpbuf[2][4];
        {
            const u64* p = xp_addr(0);
#pragma unroll
            for (int j = 0; j < 4; ++j)
                xpbuf[0][j] = __hip_atomic_load(p + j, __ATOMIC_RELAXED, __HIP_MEMORY_SCOPE_AGENT);
        }

        const u16* hrd = hb + col * PADR + quad * 8;        // A-read base (sigma layout)
        const u16* b3b = whlds + (size_t)w * 16 * 64 * 8;   // wave's tile-3 slice (constant!)
        u16* hwr = hb + (quad * 4) * PADR + w * 64 + col * 4;  // sigma-packed write base
        float* outp = out + ((size_t)(nb * 16 + quad * 4) * SS) * DD + w * 64 + col;   // layer 3
        float* out2 = out + (size_t)NN * SS * DD
                    + ((size_t)layer * NN + nb * 16 + quad * 4) * DD + w * 64 + col;

        // cross-step B3 pipeline: tile-3 LDS is never rewritten, so these reads may
        // issue in the PREVIOUS step's sigmoid phase and fly across barrier-2.
        bf16x8 b0 = *(const bf16x8*)(b3b + lane * 8);
        bf16x8 b1 = *(const bf16x8*)(b3b + 512 + lane * 8);
        bf16x8 b2 = *(const bf16x8*)(b3b + 1024 + lane * 8);

        for (int t = 0; t < SS; ++t) {
            const int cur = t & 1;
            // chunk boundary FIRST: ack chunk c as consumed. The closing barrier of
            // step t-1 (= 16c+14) was the full __syncthreads — its vmcnt(0) drain
            // retired every wave's chunk-c ring loads into registers, so the
            // producer may overwrite the slot. Ack precedes the poll (nslots=1-safe).
            if ((t & 15) == 15) {
                if (tid == 0)
                    __hip_atomic_store(&cons_done[cl * 32], (u32)((t >> 4) + 1),
                                       __ATOMIC_RELEASE, __HIP_MEMORY_SCOPE_AGENT);
            }
            // poll + prefetch xp[t+1] as early in the step as possible (max slack)
            if (t + 1 < SS) {
                if (((t + 1) & 15) == 0) {
                    const int nc = (t + 1) >> 4;
                    while (__hip_atomic_load(&prod_cnt[cl * NCHUNKS + nc], __ATOMIC_ACQUIRE,
                                             __HIP_MEMORY_SCOPE_AGENT) < FGROUPS)
                        __builtin_amdgcn_s_sleep(8);
                }
                const u64* p = xp_addr(t + 1);
#pragma unroll
                for (int j = 0; j < 4; ++j)
                    xpbuf[cur ^ 1][j] =
                        __hip_atomic_load(p + j, __ATOMIC_RELAXED, __HIP_MEMORY_SCOPE_AGENT);
            }
            // acc init from xp[t] (bias already folded in by producer)
            f32x4 acc[4];
#pragma unroll
            for (int tl = 0; tl < 4; ++tl) {
                const u64 v = xpbuf[cur][tl];
                acc[tl][0] = bf2f((u32)v);
                acc[tl][1] = bf2f((u32)(v >> 16));
                acc[tl][2] = bf2f((u32)(v >> 32));
                acc[tl][3] = bf2f((u32)(v >> 48));
            }
            // recurrent GEMM: A = h[t-1] (LDS), B = Wh (regs + LDS tile 3).
            // A-pipe 4-deep (covers ~120cyc LDS latency at ~19cyc/ks consumption,
            // only 2 waves/SIMD to overlap); B3 3-deep, cross-step-primed.
            // Statically-named rotation (rule #20: compile-time indices after unroll).
            {
                bf16x8 a0 = *(const bf16x8*)(hrd);
                bf16x8 a1 = *(const bf16x8*)(hrd + 32);
                bf16x8 a2 = *(const bf16x8*)(hrd + 64);
                bf16x8 a3 = *(const bf16x8*)(hrd + 96);
#pragma unroll
                for (int ks = 0; ks < 16; ++ks) {
                    bf16x8 an = a3, bn = b2;
                    if (ks < 12) an = *(const bf16x8*)(hrd + 32 * (ks + 4));
                    if (ks < 13) bn = *(const bf16x8*)(b3b + 512 * (ks + 3) + lane * 8);
                    acc[0] = __builtin_amdgcn_mfma_f32_16x16x32_bf16(a0, whf[ks], acc[0], 0, 0, 0);
                    acc[1] = __builtin_amdgcn_mfma_f32_16x16x32_bf16(a0, whf[16 + ks], acc[1], 0, 0, 0);
                    acc[2] = __builtin_amdgcn_mfma_f32_16x16x32_bf16(a0, whf[32 + ks], acc[2], 0, 0, 0);
                    acc[3] = __builtin_amdgcn_mfma_f32_16x16x32_bf16(a0, b0, acc[3], 0, 0, 0);
                    a0 = a1; a1 = a2; a2 = a3; a3 = an;
                    b0 = b1; b1 = b2; b2 = bn;
                }
            }
            lds_barrier();     // barrier 1: all h[t-1] reads done (LDS-only ordering)
            // sigmoid + sigma-packed h[t] publish (4 x ds_write_b64, conflict-free)
            // + global outputs (retire across steps)
#pragma unroll
            for (int i = 0; i < 4; ++i) {
                const float s0 = sigmoid_fast(acc[0][i]);
                const float s1 = sigmoid_fast(acc[1][i]);
                const float s2 = sigmoid_fast(acc[2][i]);
                const float s3 = sigmoid_fast(acc[3][i]);
                const u64 pk = (u64)f2bf(s0) | ((u64)f2bf(s1) << 16)
                             | ((u64)f2bf(s2) << 32) | ((u64)f2bf(s3) << 48);
                *(u64*)(hwr + (size_t)i * PADR) = pk;          // stored s = w*64+col*4+{0..3}
                if (layer == 3) {
                    float* o = outp + ((size_t)i * SS + t) * DD;
                    o[0] = s0; o[16] = s1; o[32] = s2; o[48] = s3;
                }
                if (t == SS - 1) {
                    float* o2 = out2 + (size_t)i * DD;
                    o2[0] = s0; o2[16] = s1; o2[32] = s2; o2[48] = s3;
                }
            }
            // Pin issue order: the 4 h-writes above MUST precede the B3 prefetch
            // below, so the counted lgkmcnt(3) (in-order DS retirement) proves the
            // writes are visible before s_barrier.
            __builtin_amdgcn_sched_barrier(0);
            // B3 prefetch for step t+1 (reads constant tile-3 region — no WAR/WAW)
            b0 = *(const bf16x8*)(b3b + lane * 8);
            b1 = *(const bf16x8*)(b3b + 512 + lane * 8);
            b2 = *(const bf16x8*)(b3b + 1024 + lane * 8);
            // barrier 2: h[t] visible. Full drain once per chunk (end of t%16==14) —
            // exactly what the t%16==15 ack's correctness argument needs. All other
            // steps: counted lgkmcnt(3) leaves ONLY the 3 B3 prefetch reads in
            // flight (oldest-first DS retirement => the 4 h-writes are done).
            if ((t & 15) == 14) __syncthreads();
            else {
                asm volatile("s_waitcnt lgkmcnt(3)" ::: "memory");
                __builtin_amdgcn_sched_barrier(0);
                __builtin_amdgcn_s_barrier();
                __builtin_amdgcn_sched_barrier(0);
            }
        }
    } else {
        // ========== persistent producers: xp = Wx x + (bx+bh) (r3/r5-proven, untouched) ==========
        const int q = blockIdx.x - NCONS;
        if (q >= NPROD_ACTIVE) return;
        const int combo = q & 31;
        const int cl = combo >> 2, fg = combo & 3;
        const int layer = cl >> 1, nb = cl & 1;
        u16* blds = (u16*)lds;   // Wx B-frags: [ct 8][ks 16][lane 64][8 bf16] = 128 KB

        // stage B = Wx[layer][fg*128 ..+128][512] as bf16 fragments in LDS (once)
        for (int r = 0; r < 16; ++r) {
            const int li = (r * 512 + tid) * 8;
            const int row = li >> 9, k0 = li & 511;
            bf16x8 v = cvt8(Wx + ((size_t)layer * DD + fg * 128 + row) * VV + k0);
            const int ct = row >> 4, fcol = row & 15, ks = k0 >> 5, qd = (k0 >> 3) & 3;
            *(bf16x8*)(blds + ((size_t)((ct * 16 + ks) * 64 + qd * 16 + fcol)) * 8) = v;
        }
        float bias[8];
#pragma unroll
        for (int ct = 0; ct < 8; ++ct) {
            const int f = layer * DD + fg * 128 + ct * 16 + col;
            bias[ct] = bx[f] + bh[f];
        }
        __syncthreads();

        for (int chunk = q >> 5; chunk < NCHUNKS; chunk += CRES) {
            // ---- compute first (ungated) ----
            const int t0 = chunk * CHUNK;
            f32x4 acc[2][8];
#pragma unroll
            for (int rt = 0; rt < 2; ++rt)
#pragma unroll
                for (int ct = 0; ct < 8; ++ct)
                    acc[rt][ct] = f32x4{bias[ct], bias[ct], bias[ct], bias[ct]};
            const float* xr0 = x + ((size_t)(nb * 16 + col) * SS + (t0 + 2 * w)) * VV + quad * 8;
#pragma unroll
            for (int ks = 0; ks < 16; ++ks) {
                bf16x8 a0 = cvt8(xr0 + 32 * ks);
                bf16x8 a1 = cvt8(xr0 + VV + 32 * ks);
#pragma unroll
                for (int ct = 0; ct < 8; ++ct) {
                    bf16x8 b = *(const bf16x8*)(blds + ((size_t)((ct * 16 + ks) * 64 + lane)) * 8);
                    acc[0][ct] = __builtin_amdgcn_mfma_f32_16x16x32_bf16(a0, b, acc[0][ct], 0, 0, 0);
                    acc[1][ct] = __builtin_amdgcn_mfma_f32_16x16x32_bf16(a1, b, acc[1][ct], 0, 0, 0);
                }
            }
            // ---- bounded-buffer gate: lazy poll (s_sleep 127 ~3.4 us) — producers
            // run ~7 chunks ahead, so wake latency is off-path and the agent-acquire
            // storm on the cons_done lines stays ~8x reduced. ----
            const int slot = chunk % nslots;
            if (chunk >= nslots && tid == 0) {
                while ((int)__hip_atomic_load(&cons_done[cl * 32], __ATOMIC_ACQUIRE,
                                              __HIP_MEMORY_SCOPE_AGENT) < chunk - nslots + 1)
                    __builtin_amdgcn_s_sleep(127);
            }
            __syncthreads();   // gate known to all waves
            // ---- store in consumer C-frag order: bf16x4 packed u64, agent-scope ----
#pragma unroll
            for (int rt = 0; rt < 2; ++rt) {
                char* base = ring + ((size_t)(slot * NCONS + cl) * CHUNK + (2 * w + rt)) * (8 * 64 * 32);
#pragma unroll
                for (int ct = 0; ct < 8; ++ct) {
                    const int gct = fg * 8 + ct, wc = gct >> 2, tl = gct & 3;
                    const f32x4 a = acc[rt][ct];
                    u64 v = (u64)f2bf(a[0]) | ((u64)f2bf(a[1]) << 16)
                          | ((u64)f2bf(a[2]) << 32) | ((u64)f2bf(a[3]) << 48);
                    __hip_atomic_store((u64*)(base + ((size_t)wc * 64 + lane) * 32 + tl * 8), v,
                                       __ATOMIC_RELAXED, __HIP_MEMORY_SCOPE_AGENT);
                }
            }
            __syncthreads();   // drains all waves' stores (vmcnt0 before s_barrier)
            if (tid == 0)
                __hip_atomic_fetch_add(&prod_cnt[cl * NCHUNKS + chunk], 1u,
                                       __ATOMIC_RELEASE, __HIP_MEMORY_SCOPE_AGENT);
        }
    }
}

extern "C" void kernel_launch(void* const* d_in, const int* in_sizes, int n_in,
                              void* d_out, int out_size, void* d_ws, size_t ws_size,
                              hipStream_t stream) {
    const float* x  = (const float*)d_in[0];
    const float* Wx = (const float*)d_in[1];
    const float* bx = (const float*)d_in[2];
    const float* Wh = (const float*)d_in[3];
    const float* bh = (const float*)d_in[4];
    float* out = (float*)d_out;
    char* ws = (char*)d_ws;

    int nslots = 1;
    if (ws_size > RING_OFF + SLOT_BYTES) {
        size_t n = (ws_size - RING_OFF) / SLOT_BYTES;
        nslots = (int)(n > 8 ? 8 : n);
    }
    hipFuncSetAttribute((const void*)rnn_fused,
                        hipFuncAttributeMaxDynamicSharedMemorySize, LDS_BYTES);
    hipMemsetAsync(ws, 0, RING_OFF, stream);   // zero flags (ws is re-poisoned each call)
    rnn_fused<<<dim3(NBLOCKS), dim3(512), LDS_BYTES, stream>>>(x, Wx, bx, Wh, bh, out, ws, nslots);
}